// Round 6
// baseline (484.056 us; speedup 1.0000x reference)
//
#include <hip/hip_runtime.h>

#define NQ 4096
#define NM 8192
#define DK 128
#define DV 512
#define BATCH 2

typedef __attribute__((ext_vector_type(8))) short short8;
typedef __attribute__((ext_vector_type(4))) float f32x4;
typedef unsigned short ushort_t;

static __device__ __forceinline__ unsigned short f2bf(float x) {
    union { float f; unsigned int u; } c; c.f = x;
    unsigned int u = c.u;
    return (unsigned short)((u + 0x7FFFu + ((u >> 16) & 1u)) >> 16);
}
static __device__ __forceinline__ float bf2f(unsigned short h) {
    union { unsigned int u; float f; } c; c.u = ((unsigned int)h) << 16;
    return c.f;
}

// ---------------------------------------------------------------------------
// scan: per-batch compaction of mmask (shfl wave scans).
// ---------------------------------------------------------------------------
__global__ __launch_bounds__(1024) void scan_kernel(
    const int* __restrict__ qmask, const int* __restrict__ mmask,
    int* __restrict__ cidx, int* __restrict__ cpos,
    int* __restrict__ cnts, int* __restrict__ qflags) {
    const int b = blockIdx.x;
    const int t = threadIdx.x;
    const int lane = t & 63;
    const int w = t >> 6;
    __shared__ int wsum[16];
    __shared__ int qsh;

    const int* mp = mmask + b * NM;
    const int base = t * 8;
    int val[8];
#pragma unroll
    for (int i = 0; i < 8; ++i) val[i] = (mp[base + i] != 0);
    int c0 = 0;
#pragma unroll
    for (int i = 0; i < 8; ++i) c0 += val[i];

    int c = c0;
#pragma unroll
    for (int off = 1; off < 64; off <<= 1) {
        int n = __shfl_up(c, off, 64);
        if (lane >= off) c += n;
    }
    if (lane == 63) wsum[w] = c;
    if (t == 0) qsh = 0;
    __syncthreads();
    if (t == 0) {
        int s = 0;
#pragma unroll
        for (int i = 0; i < 16; ++i) { s += wsum[i]; wsum[i] = s; }
    }
    __syncthreads();
    const int wbase = (w == 0) ? 0 : wsum[w - 1];
    int run = wbase + (c - c0);
#pragma unroll
    for (int i = 0; i < 8; ++i) {
        int m = base + i;
        cpos[b * NM + m] = run;
        if (val[i]) { cidx[b * NM + run] = m; ++run; }
    }

    int qa = 0;
    for (int i = t; i < NQ; i += 1024) qa |= (qmask[b * NQ + i] != 0);
    if (qa) atomicOr(&qsh, 1);
    __syncthreads();
    if (t == 0) { cnts[b] = wsum[15]; qflags[b] = qsh; }
}

// ---------------------------------------------------------------------------
// prep Q: transpose [B][DK][NQ] fp32 -> [B][q][DK] bf16 hi/lo
// ---------------------------------------------------------------------------
__global__ __launch_bounds__(256) void prep_q_kernel(
    const float* __restrict__ src, ushort_t* __restrict__ hi,
    ushort_t* __restrict__ lo) {
    const int b = blockIdx.z;
    const int d0 = blockIdx.y * 32;
    const int n0 = blockIdx.x * 32;
    __shared__ float t32[32][33];
    for (int l = threadIdx.x; l < 1024; l += 256) {
        int r = l >> 5, c = l & 31;
        t32[r][c] = src[((size_t)b * DK + d0 + r) * NQ + n0 + c];
    }
    __syncthreads();
    for (int l = threadIdx.x; l < 1024; l += 256) {
        int r = l >> 5, c = l & 31;
        float f = t32[c][r];
        unsigned short h = f2bf(f);
        unsigned short lw = f2bf(f - bf2f(h));
        size_t off = ((size_t)b * NQ + n0 + r) * DK + d0 + c;
        hi[off] = h;
        lo[off] = lw;
    }
}

// ---------------------------------------------------------------------------
// prep K: transpose + compacting gather [B][DK][NM] -> [B][m'][DK] hi/lo
// ---------------------------------------------------------------------------
__global__ __launch_bounds__(256) void prep_k_kernel(
    const float* __restrict__ src, const int* __restrict__ mmask,
    const int* __restrict__ cpos,
    ushort_t* __restrict__ hi, ushort_t* __restrict__ lo) {
    const int b = blockIdx.z;
    const int d0 = blockIdx.y * 32;
    const int n0 = blockIdx.x * 32;
    __shared__ float t32[32][33];
    for (int l = threadIdx.x; l < 1024; l += 256) {
        int r = l >> 5, c = l & 31;
        t32[r][c] = src[((size_t)b * DK + d0 + r) * NM + n0 + c];
    }
    __syncthreads();
    for (int l = threadIdx.x; l < 1024; l += 256) {
        int r = l >> 5, c = l & 31;
        int m = n0 + r;
        if (mmask[b * NM + m] != 0) {
            int pos = cpos[b * NM + m];
            float f = t32[c][r];
            unsigned short h = f2bf(f);
            unsigned short lw = f2bf(f - bf2f(h));
            size_t off = ((size_t)b * NM + pos) * DK + d0 + c;
            hi[off] = h;
            lo[off] = lw;
        }
    }
}

// ---------------------------------------------------------------------------
// prep V: compacting gather + convert [B][DV][NM] fp32 -> [B][DV][m'] bf16
// zero-pads [cnt, NM).
// ---------------------------------------------------------------------------
__global__ __launch_bounds__(256) void prep_v_kernel(
    const float* __restrict__ src, const int* __restrict__ cidx,
    const int* __restrict__ cnts, ushort_t* __restrict__ dst) {
    const size_t idx = (size_t)blockIdx.x * 256 + threadIdx.x;
    const int mi4 = (int)((idx % (NM / 4)) * 4);
    const int dv = (int)((idx / (NM / 4)) % DV);
    const int b = (int)(idx / ((size_t)(NM / 4) * DV));
    const int cnt = cnts[b];

    int4 ci = *(const int4*)(cidx + b * NM + mi4);
    int i0 = (mi4 + 0 < cnt) ? ci.x : 0;
    int i1 = (mi4 + 1 < cnt) ? ci.y : 0;
    int i2 = (mi4 + 2 < cnt) ? ci.z : 0;
    int i3 = (mi4 + 3 < cnt) ? ci.w : 0;
    const float* row = src + ((size_t)b * DV + dv) * NM;
    ushort4 o;
    o.x = (mi4 + 0 < cnt) ? f2bf(row[i0]) : (ushort_t)0;
    o.y = (mi4 + 1 < cnt) ? f2bf(row[i1]) : (ushort_t)0;
    o.z = (mi4 + 2 < cnt) ? f2bf(row[i2]) : (ushort_t)0;
    o.w = (mi4 + 3 < cnt) ? f2bf(row[i3]) : (ushort_t)0;
    *(ushort4*)(dst + ((size_t)b * DV + dv) * NM + mi4) = o;
}

// ---------------------------------------------------------------------------
// fused main: two-sweep attention over compacted rows.
//  sweep1: per-wave register-only (max, sumexp) over all m — NO barriers.
//  combine: one LDS reduction -> gmax[q], grinv[q] (gating folded in).
//  sweep2: P = exp(s-gmax) -> parity-buffered LDS -> PV; ONE barrier/iter.
// block: 512 thr (8 waves), q-tile 32, dv-half 256, grid 512 (2 blocks/CU).
// wave w: QK rows m = mb + [16w,16w+16); PV dv rows dvh*256 + [32w,32w+32).
// ---------------------------------------------------------------------------
__global__ __launch_bounds__(512, 4) void attn_fused_kernel(
    const ushort_t* __restrict__ Qhi, const ushort_t* __restrict__ Qlo,
    const ushort_t* __restrict__ Khi, const ushort_t* __restrict__ Klo,
    const ushort_t* __restrict__ Vb, const int* __restrict__ cnts,
    const int* __restrict__ qflags, const int* __restrict__ qmask,
    float* __restrict__ out) {
    const int t = threadIdx.x;
    const int lane = t & 63;
    const int w = t >> 6;          // 0..7
    const int quad = lane >> 4;
    const int col = lane & 15;
    // XCD swizzle: combo c = bid&3 lands on XCDs {c, c+4}; per-combo K+V
    // working set ~4 MB ≈ one XCD's L2.
    const int bid = blockIdx.x;
    const int cmb = bid & 3;
    const int b = cmb >> 1;
    const int dvh = cmb & 1;
    const int qb = (bid >> 2) * 32;

    const int cnt = cnts[b];
    const int nit = (cnt + 127) >> 7;

    __shared__ __align__(16) ushort_t P_s[2][32][136];
    __shared__ float red_m[8][32], red_l[8][32];
    __shared__ float gmax_s[32], grinv_s[32];

    // resident Q fragments (B-operand)
    short8 qfh[2][4], qfl[2][4];
    {
        const ushort_t* qhp = Qhi + ((size_t)b * NQ + qb) * DK;
        const ushort_t* qlp = Qlo + ((size_t)b * NQ + qb) * DK;
#pragma unroll
        for (int qt = 0; qt < 2; ++qt)
#pragma unroll
            for (int ks = 0; ks < 4; ++ks) {
                size_t off = (size_t)(qt * 16 + col) * DK + ks * 32 + quad * 8;
                qfh[qt][ks] = *(const short8*)(qhp + off);
                qfl[qt][ks] = *(const short8*)(qlp + off);
            }
    }

    const ushort_t* khp = Khi + ((size_t)b * NM + w * 16 + col) * DK + quad * 8;
    const ushort_t* klp = Klo + ((size_t)b * NM + w * 16 + col) * DK + quad * 8;
    const ushort_t* vp  = Vb + ((size_t)b * DV + dvh * 256 + w * 32 + col) * NM + quad * 8;

    const f32x4 zero4 = {0.f, 0.f, 0.f, 0.f};

    // ================= sweep 1: stats, no barriers =================
    float mrun[2] = {-3.0e38f, -3.0e38f};
    float lrun[2] = {0.0f, 0.0f};
    for (int it = 0; it < nit; ++it) {
        const int mb = it * 128;
        f32x4 accS[2];
        accS[0] = zero4; accS[1] = zero4;
#pragma unroll
        for (int ks = 0; ks < 4; ++ks) {
            short8 ah = *(const short8*)(khp + (size_t)mb * DK + ks * 32);
            short8 al = *(const short8*)(klp + (size_t)mb * DK + ks * 32);
            accS[0] = __builtin_amdgcn_mfma_f32_16x16x32_bf16(ah, qfh[0][ks], accS[0], 0, 0, 0);
            accS[1] = __builtin_amdgcn_mfma_f32_16x16x32_bf16(ah, qfh[1][ks], accS[1], 0, 0, 0);
            accS[0] = __builtin_amdgcn_mfma_f32_16x16x32_bf16(ah, qfl[0][ks], accS[0], 0, 0, 0);
            accS[1] = __builtin_amdgcn_mfma_f32_16x16x32_bf16(ah, qfl[1][ks], accS[1], 0, 0, 0);
            accS[0] = __builtin_amdgcn_mfma_f32_16x16x32_bf16(al, qfh[0][ks], accS[0], 0, 0, 0);
            accS[1] = __builtin_amdgcn_mfma_f32_16x16x32_bf16(al, qfh[1][ks], accS[1], 0, 0, 0);
        }
        const int mrow = mb + w * 16 + quad * 4;
#pragma unroll
        for (int qt = 0; qt < 2; ++qt) {
            float s[4];
            float tm = -3.0e38f;
#pragma unroll
            for (int r = 0; r < 4; ++r) {
                s[r] = (mrow + r < cnt) ? accS[qt][r] * 40.0f : -3.0e38f;
                tm = fmaxf(tm, s[r]);
            }
            tm = fmaxf(tm, __shfl_xor(tm, 16, 64));
            tm = fmaxf(tm, __shfl_xor(tm, 32, 64));
            float mn = fmaxf(mrun[qt], tm);
            float ps = 0.f;
#pragma unroll
            for (int r = 0; r < 4; ++r)
                ps += (mrow + r < cnt) ? __expf(s[r] - mn) : 0.0f;
            ps += __shfl_xor(ps, 16, 64);
            ps += __shfl_xor(ps, 32, 64);
            lrun[qt] = lrun[qt] * __expf(mrun[qt] - mn) + ps;
            mrun[qt] = mn;
        }
    }
    if (lane < 16) {
        red_m[w][col] = mrun[0];      red_l[w][col] = lrun[0];
        red_m[w][16 + col] = mrun[1]; red_l[w][16 + col] = lrun[1];
    }
    __syncthreads();
    if (t < 32) {
        float M = -3.0e38f;
#pragma unroll
        for (int ww = 0; ww < 8; ++ww) M = fmaxf(M, red_m[ww][t]);
        float L = 0.f;
#pragma unroll
        for (int ww = 0; ww < 8; ++ww)
            L += red_l[ww][t] * __expf(red_m[ww][t] - M);
        bool valid = (qflags[b] != 0) && (cnt > 0) && (qmask[b * NQ + qb + t] != 0);
        gmax_s[t] = M;
        grinv_s[t] = valid ? 1.0f / L : 0.0f;
    }
    __syncthreads();
    const float gmax[2] = {gmax_s[col], gmax_s[16 + col]};
    const float grinv[2] = {grinv_s[col], grinv_s[16 + col]};

    // ================= sweep 2: P + PV, one barrier/iter =================
    f32x4 accO[2][2];   // [vt][qt]
#pragma unroll
    for (int vt = 0; vt < 2; ++vt)
#pragma unroll
        for (int qt = 0; qt < 2; ++qt) accO[vt][qt] = zero4;

    for (int it = 0; it < nit; ++it) {
        const int mb = it * 128;
        const int par = it & 1;

        f32x4 accS[2];
        accS[0] = zero4; accS[1] = zero4;
#pragma unroll
        for (int ks = 0; ks < 4; ++ks) {
            short8 ah = *(const short8*)(khp + (size_t)mb * DK + ks * 32);
            short8 al = *(const short8*)(klp + (size_t)mb * DK + ks * 32);
            accS[0] = __builtin_amdgcn_mfma_f32_16x16x32_bf16(ah, qfh[0][ks], accS[0], 0, 0, 0);
            accS[1] = __builtin_amdgcn_mfma_f32_16x16x32_bf16(ah, qfh[1][ks], accS[1], 0, 0, 0);
            accS[0] = __builtin_amdgcn_mfma_f32_16x16x32_bf16(ah, qfl[0][ks], accS[0], 0, 0, 0);
            accS[1] = __builtin_amdgcn_mfma_f32_16x16x32_bf16(ah, qfl[1][ks], accS[1], 0, 0, 0);
            accS[0] = __builtin_amdgcn_mfma_f32_16x16x32_bf16(al, qfh[0][ks], accS[0], 0, 0, 0);
            accS[1] = __builtin_amdgcn_mfma_f32_16x16x32_bf16(al, qfh[1][ks], accS[1], 0, 0, 0);
        }
        const int mrow = mb + w * 16 + quad * 4;
#pragma unroll
        for (int qt = 0; qt < 2; ++qt) {
            float p[4];
#pragma unroll
            for (int r = 0; r < 4; ++r) {
                float s = accS[qt][r] * 40.0f;
                p[r] = (mrow + r < cnt) ? __expf(s - gmax[qt]) : 0.0f;
            }
            ushort4 pk;
            pk.x = f2bf(p[0]); pk.y = f2bf(p[1]);
            pk.z = f2bf(p[2]); pk.w = f2bf(p[3]);
            *(ushort4*)&P_s[par][qt * 16 + col][w * 16 + quad * 4] = pk;
        }
        __syncthreads();   // single barrier: P[par] published (parity protects reuse)

#pragma unroll
        for (int ks = 0; ks < 4; ++ks) {
            short8 b0 = *(const short8*)&P_s[par][col][ks * 32 + quad * 8];
            short8 b1 = *(const short8*)&P_s[par][16 + col][ks * 32 + quad * 8];
#pragma unroll
            for (int vt = 0; vt < 2; ++vt) {
                short8 av = *(const short8*)(vp + (size_t)(vt * 16) * NM + mb + ks * 32);
                accO[vt][0] = __builtin_amdgcn_mfma_f32_16x16x32_bf16(av, b0, accO[vt][0], 0, 0, 0);
                accO[vt][1] = __builtin_amdgcn_mfma_f32_16x16x32_bf16(av, b1, accO[vt][1], 0, 0, 0);
            }
        }
    }

    // ---- epilogue: final normalized fp32 output (no combine pass) ----
#pragma unroll
    for (int qt = 0; qt < 2; ++qt) {
        const int q = qb + qt * 16 + col;
        const float g = grinv[qt];
#pragma unroll
        for (int vt = 0; vt < 2; ++vt)
#pragma unroll
            for (int r = 0; r < 4; ++r) {
                int dv = dvh * 256 + w * 32 + vt * 16 + quad * 4 + r;
                out[((size_t)b * DV + dv) * NQ + q] = accO[vt][qt][r] * g;
            }
    }
}

// ---------------------------------------------------------------------------
extern "C" void kernel_launch(void* const* d_in, const int* in_sizes, int n_in,
                              void* d_out, int out_size, void* d_ws, size_t ws_size,
                              hipStream_t stream) {
    const float* qkey  = (const float*)d_in[0];
    // d_in[1] (qval) unused by the reference
    const int*   qmask = (const int*)d_in[2];
    const float* mkey  = (const float*)d_in[3];
    const float* mval  = (const float*)d_in[4];
    const int*   mmask = (const int*)d_in[5];
    float* out = (float*)d_out;

    char* ws = (char*)d_ws;
    size_t off = 0;
    const size_t QS = (size_t)BATCH * NQ * DK * 2;
    const size_t KS = (size_t)BATCH * NM * DK * 2;
    const size_t VS = (size_t)BATCH * DV * NM * 2;
    ushort_t* Qhi = (ushort_t*)(ws + off); off += QS;
    ushort_t* Qlo = (ushort_t*)(ws + off); off += QS;
    ushort_t* Khi = (ushort_t*)(ws + off); off += KS;
    ushort_t* Klo = (ushort_t*)(ws + off); off += KS;
    ushort_t* Vc  = (ushort_t*)(ws + off); off += VS;
    int* cidx     = (int*)(ws + off); off += (size_t)BATCH * NM * 4;
    int* cpos     = (int*)(ws + off); off += (size_t)BATCH * NM * 4;
    int* cnts     = (int*)(ws + off); off += 64;
    int* qflags   = (int*)(ws + off); off += 64;

    scan_kernel<<<BATCH, 1024, 0, stream>>>(qmask, mmask, cidx, cpos, cnts, qflags);

    dim3 gq(NQ / 32, DK / 32, BATCH);
    prep_q_kernel<<<gq, 256, 0, stream>>>(qkey, Qhi, Qlo);
    dim3 gk(NM / 32, DK / 32, BATCH);
    prep_k_kernel<<<gk, 256, 0, stream>>>(mkey, mmask, cpos, Khi, Klo);

    const int vblocks = (int)(((size_t)BATCH * DV * (NM / 4)) / 256);
    prep_v_kernel<<<vblocks, 256, 0, stream>>>(mval, cidx, cnts, Vc);

    // 512 blocks (2/CU): x = 4 combos * 128 q-tiles, swizzle-decoded in-kernel
    attn_fused_kernel<<<(NQ / 32) * 4, 512, 0, stream>>>(
        Qhi, Qlo, Khi, Klo, Vc, cnts, qflags, qmask, out);
}

// Round 7
// 431.479 us; speedup vs baseline: 1.1219x; 1.1219x over previous
//
#include <hip/hip_runtime.h>

#define NQ 4096
#define NM 8192
#define DK 128
#define DV 512
#define BATCH 2
#define NCHUNK 4
#define CHUNK (NM / NCHUNK)

typedef __attribute__((ext_vector_type(8))) short short8;
typedef __attribute__((ext_vector_type(4))) float f32x4;
typedef unsigned short ushort_t;

static __device__ __forceinline__ unsigned short f2bf(float x) {
    union { float f; unsigned int u; } c; c.f = x;
    unsigned int u = c.u;
    return (unsigned short)((u + 0x7FFFu + ((u >> 16) & 1u)) >> 16);
}
static __device__ __forceinline__ float bf2f(unsigned short h) {
    union { unsigned int u; float f; } c; c.u = ((unsigned int)h) << 16;
    return c.f;
}

// ---------------------------------------------------------------------------
// scan: per-batch compaction of mmask (shfl wave scans).
// ---------------------------------------------------------------------------
__global__ __launch_bounds__(1024) void scan_kernel(
    const int* __restrict__ qmask, const int* __restrict__ mmask,
    int* __restrict__ cidx, int* __restrict__ cpos,
    int* __restrict__ cnts, int* __restrict__ qflags) {
    const int b = blockIdx.x;
    const int t = threadIdx.x;
    const int lane = t & 63;
    const int w = t >> 6;
    __shared__ int wsum[16];
    __shared__ int qsh;

    const int* mp = mmask + b * NM;
    const int base = t * 8;
    int val[8];
#pragma unroll
    for (int i = 0; i < 8; ++i) val[i] = (mp[base + i] != 0);
    int c0 = 0;
#pragma unroll
    for (int i = 0; i < 8; ++i) c0 += val[i];

    int c = c0;
#pragma unroll
    for (int off = 1; off < 64; off <<= 1) {
        int n = __shfl_up(c, off, 64);
        if (lane >= off) c += n;
    }
    if (lane == 63) wsum[w] = c;
    if (t == 0) qsh = 0;
    __syncthreads();
    if (t == 0) {
        int s = 0;
#pragma unroll
        for (int i = 0; i < 16; ++i) { s += wsum[i]; wsum[i] = s; }
    }
    __syncthreads();
    const int wbase = (w == 0) ? 0 : wsum[w - 1];
    int run = wbase + (c - c0);
#pragma unroll
    for (int i = 0; i < 8; ++i) {
        int m = base + i;
        cpos[b * NM + m] = run;
        if (val[i]) { cidx[b * NM + run] = m; ++run; }
    }

    int qa = 0;
    for (int i = t; i < NQ; i += 1024) qa |= (qmask[b * NQ + i] != 0);
    if (qa) atomicOr(&qsh, 1);
    __syncthreads();
    if (t == 0) { cnts[b] = wsum[15]; qflags[b] = qsh; }
}

// ---------------------------------------------------------------------------
// prep Q: transpose [B][DK][NQ] fp32 -> [B][q][DK] bf16 hi/lo
// ---------------------------------------------------------------------------
__global__ __launch_bounds__(256) void prep_q_kernel(
    const float* __restrict__ src, ushort_t* __restrict__ hi,
    ushort_t* __restrict__ lo) {
    const int b = blockIdx.z;
    const int d0 = blockIdx.y * 32;
    const int n0 = blockIdx.x * 32;
    __shared__ float t32[32][33];
    for (int l = threadIdx.x; l < 1024; l += 256) {
        int r = l >> 5, c = l & 31;
        t32[r][c] = src[((size_t)b * DK + d0 + r) * NQ + n0 + c];
    }
    __syncthreads();
    for (int l = threadIdx.x; l < 1024; l += 256) {
        int r = l >> 5, c = l & 31;
        float f = t32[c][r];
        unsigned short h = f2bf(f);
        unsigned short lw = f2bf(f - bf2f(h));
        size_t off = ((size_t)b * NQ + n0 + r) * DK + d0 + c;
        hi[off] = h;
        lo[off] = lw;
    }
}

// ---------------------------------------------------------------------------
// prep K: transpose + compacting gather [B][DK][NM] -> [B][m'][DK] hi/lo
// ---------------------------------------------------------------------------
__global__ __launch_bounds__(256) void prep_k_kernel(
    const float* __restrict__ src, const int* __restrict__ mmask,
    const int* __restrict__ cpos,
    ushort_t* __restrict__ hi, ushort_t* __restrict__ lo) {
    const int b = blockIdx.z;
    const int d0 = blockIdx.y * 32;
    const int n0 = blockIdx.x * 32;
    __shared__ float t32[32][33];
    for (int l = threadIdx.x; l < 1024; l += 256) {
        int r = l >> 5, c = l & 31;
        t32[r][c] = src[((size_t)b * DK + d0 + r) * NM + n0 + c];
    }
    __syncthreads();
    for (int l = threadIdx.x; l < 1024; l += 256) {
        int r = l >> 5, c = l & 31;
        int m = n0 + r;
        if (mmask[b * NM + m] != 0) {
            int pos = cpos[b * NM + m];
            float f = t32[c][r];
            unsigned short h = f2bf(f);
            unsigned short lw = f2bf(f - bf2f(h));
            size_t off = ((size_t)b * NM + pos) * DK + d0 + c;
            hi[off] = h;
            lo[off] = lw;
        }
    }
}

// ---------------------------------------------------------------------------
// prep V: compacting gather + convert [B][DV][NM] fp32 -> [B][DV][m'] bf16
// ---------------------------------------------------------------------------
__global__ __launch_bounds__(256) void prep_v_kernel(
    const float* __restrict__ src, const int* __restrict__ cidx,
    const int* __restrict__ cnts, ushort_t* __restrict__ dst) {
    const size_t idx = (size_t)blockIdx.x * 256 + threadIdx.x;
    const int mi4 = (int)((idx % (NM / 4)) * 4);
    const int dv = (int)((idx / (NM / 4)) % DV);
    const int b = (int)(idx / ((size_t)(NM / 4) * DV));
    const int cnt = cnts[b];

    int4 ci = *(const int4*)(cidx + b * NM + mi4);
    int i0 = (mi4 + 0 < cnt) ? ci.x : 0;
    int i1 = (mi4 + 1 < cnt) ? ci.y : 0;
    int i2 = (mi4 + 2 < cnt) ? ci.z : 0;
    int i3 = (mi4 + 3 < cnt) ? ci.w : 0;
    const float* row = src + ((size_t)b * DV + dv) * NM;
    ushort4 o;
    o.x = (mi4 + 0 < cnt) ? f2bf(row[i0]) : (ushort_t)0;
    o.y = (mi4 + 1 < cnt) ? f2bf(row[i1]) : (ushort_t)0;
    o.z = (mi4 + 2 < cnt) ? f2bf(row[i2]) : (ushort_t)0;
    o.w = (mi4 + 3 < cnt) ? f2bf(row[i3]) : (ushort_t)0;
    *(ushort4*)(dst + ((size_t)b * DV + dv) * NM + mi4) = o;
}

// ---------------------------------------------------------------------------
// stats: per-(q-tile, m-chunk) softmax stats. ZERO barriers / shfls in loop:
// lane-local online (m,l); single merge at the end. grid (128, NCHUNK, B),
// 256 thr (4 waves x 16 m-rows, m-tile 64).
// ---------------------------------------------------------------------------
__global__ __launch_bounds__(256, 4) void stats_kernel(
    const ushort_t* __restrict__ Qhi, const ushort_t* __restrict__ Qlo,
    const ushort_t* __restrict__ Khi, const ushort_t* __restrict__ Klo,
    const int* __restrict__ cnts,
    float* __restrict__ mpart, float* __restrict__ lpart) {
    const int t = threadIdx.x;
    const int lane = t & 63;
    const int w = t >> 6;          // 0..3
    const int quad = lane >> 4;
    const int col = lane & 15;
    const int qb = blockIdx.x * 32;
    const int chunk = blockIdx.y;
    const int b = blockIdx.z;

    const int cnt = cnts[b];
    const int s0 = chunk * CHUNK;
    int lim = (cnt + 63) & ~63;
    if (lim > s0 + CHUNK) lim = s0 + CHUNK;

    __shared__ float red_m[4][32], red_l[4][32];

    short8 qfh[2][4], qfl[2][4];
    {
        const ushort_t* qhp = Qhi + ((size_t)b * NQ + qb) * DK;
        const ushort_t* qlp = Qlo + ((size_t)b * NQ + qb) * DK;
#pragma unroll
        for (int qt = 0; qt < 2; ++qt)
#pragma unroll
            for (int ks = 0; ks < 4; ++ks) {
                size_t off = (size_t)(qt * 16 + col) * DK + ks * 32 + quad * 8;
                qfh[qt][ks] = *(const short8*)(qhp + off);
                qfl[qt][ks] = *(const short8*)(qlp + off);
            }
    }

    const ushort_t* khp = Khi + ((size_t)b * NM + w * 16 + col) * DK + quad * 8;
    const ushort_t* klp = Klo + ((size_t)b * NM + w * 16 + col) * DK + quad * 8;

    const f32x4 zero4 = {0.f, 0.f, 0.f, 0.f};
    float mloc[2] = {-3.0e38f, -3.0e38f};
    float lloc[2] = {0.0f, 0.0f};

    for (int mb = s0; mb < lim; mb += 64) {
        f32x4 accS[2];
        accS[0] = zero4; accS[1] = zero4;
#pragma unroll
        for (int ks = 0; ks < 4; ++ks) {
            short8 ah = *(const short8*)(khp + (size_t)mb * DK + ks * 32);
            short8 al = *(const short8*)(klp + (size_t)mb * DK + ks * 32);
            accS[0] = __builtin_amdgcn_mfma_f32_16x16x32_bf16(ah, qfh[0][ks], accS[0], 0, 0, 0);
            accS[1] = __builtin_amdgcn_mfma_f32_16x16x32_bf16(ah, qfh[1][ks], accS[1], 0, 0, 0);
            accS[0] = __builtin_amdgcn_mfma_f32_16x16x32_bf16(ah, qfl[0][ks], accS[0], 0, 0, 0);
            accS[1] = __builtin_amdgcn_mfma_f32_16x16x32_bf16(ah, qfl[1][ks], accS[1], 0, 0, 0);
            accS[0] = __builtin_amdgcn_mfma_f32_16x16x32_bf16(al, qfh[0][ks], accS[0], 0, 0, 0);
            accS[1] = __builtin_amdgcn_mfma_f32_16x16x32_bf16(al, qfh[1][ks], accS[1], 0, 0, 0);
        }
        const int mrow = mb + w * 16 + quad * 4;
#pragma unroll
        for (int qt = 0; qt < 2; ++qt) {
            float s[4];
            float tm = -3.0e38f;
#pragma unroll
            for (int r = 0; r < 4; ++r) {
                s[r] = (mrow + r < cnt) ? accS[qt][r] * 40.0f : -3.0e38f;
                tm = fmaxf(tm, s[r]);
            }
            float mn = fmaxf(mloc[qt], tm);
            float ps = 0.f;
#pragma unroll
            for (int r = 0; r < 4; ++r)
                ps += (mrow + r < cnt) ? __expf(s[r] - mn) : 0.0f;
            lloc[qt] = lloc[qt] * __expf(mloc[qt] - mn) + ps;
            mloc[qt] = mn;
        }
    }

    // merge across quads (lanes sharing col) via shfl
#pragma unroll
    for (int qt = 0; qt < 2; ++qt) {
        float m = mloc[qt], l = lloc[qt];
#pragma unroll
        for (int d = 16; d <= 32; d <<= 1) {
            float mo = __shfl_xor(m, d, 64);
            float lo = __shfl_xor(l, d, 64);
            float M = fmaxf(m, mo);
            l = l * __expf(m - M) + lo * __expf(mo - M);
            m = M;
        }
        if (lane < 16) { red_m[w][qt * 16 + col] = m; red_l[w][qt * 16 + col] = l; }
    }
    __syncthreads();
    if (t < 32) {
        float M = -3.0e38f;
#pragma unroll
        for (int ww = 0; ww < 4; ++ww) M = fmaxf(M, red_m[ww][t]);
        float L = 0.f;
#pragma unroll
        for (int ww = 0; ww < 4; ++ww)
            L += red_l[ww][t] * __expf(red_m[ww][t] - M);
        size_t so = ((size_t)(b * NCHUNK + chunk)) * NQ + qb + t;
        mpart[so] = M;
        lpart[so] = L;
    }
}

// ---------------------------------------------------------------------------
// pv: recompute S, P = exp(s - gmax), PV, normalized write. q-tile 32,
// dv-split 2 (256 dv), m-tile 64, 256 thr (4 waves), 2 blocks/CU, 1 barrier
// per iter. V for iter it loaded BEFORE QK (held across the barrier); K for
// it+1 prefetched during it. XCD-swizzled (b, dvh) decode.
// ---------------------------------------------------------------------------
__global__ __launch_bounds__(256, 2) void pv_kernel(
    const ushort_t* __restrict__ Qhi, const ushort_t* __restrict__ Qlo,
    const ushort_t* __restrict__ Khi, const ushort_t* __restrict__ Klo,
    const ushort_t* __restrict__ Vb, const int* __restrict__ cnts,
    const int* __restrict__ qflags, const int* __restrict__ qmask,
    const float* __restrict__ mpart, const float* __restrict__ lpart,
    float* __restrict__ out) {
    const int t = threadIdx.x;
    const int lane = t & 63;
    const int w = t >> 6;          // 0..3
    const int quad = lane >> 4;
    const int col = lane & 15;
    const int bid = blockIdx.x;
    const int cmb = bid & 3;
    const int b = cmb >> 1;
    const int dvh = cmb & 1;
    const int qb = (bid >> 2) * 32;

    const int cnt = cnts[b];
    const int nit = (cnt + 63) >> 6;

    __shared__ __align__(16) ushort_t P_s[2][32][68];
    __shared__ float gmax_s[32], grinv_s[32];

    // inline combine of the NCHUNK partial stats
    if (t < 32) {
        const int q = qb + t;
        float M = -3.0e38f, L = 0.f;
#pragma unroll
        for (int c = 0; c < NCHUNK; ++c) {
            size_t so = ((size_t)(b * NCHUNK + c)) * NQ + q;
            float mc = mpart[so], lc = lpart[so];
            float Mn = fmaxf(M, mc);
            L = L * __expf(M - Mn) + lc * __expf(mc - Mn);
            M = Mn;
        }
        bool valid = (qflags[b] != 0) && (cnt > 0) && (qmask[b * NQ + q] != 0) && (L > 0.f);
        gmax_s[t] = M;
        grinv_s[t] = valid ? 1.0f / L : 0.0f;
    }

    short8 qfh[2][4], qfl[2][4];
    {
        const ushort_t* qhp = Qhi + ((size_t)b * NQ + qb) * DK;
        const ushort_t* qlp = Qlo + ((size_t)b * NQ + qb) * DK;
#pragma unroll
        for (int qt = 0; qt < 2; ++qt)
#pragma unroll
            for (int ks = 0; ks < 4; ++ks) {
                size_t off = (size_t)(qt * 16 + col) * DK + ks * 32 + quad * 8;
                qfh[qt][ks] = *(const short8*)(qhp + off);
                qfl[qt][ks] = *(const short8*)(qlp + off);
            }
    }
    __syncthreads();
    const float gmax[2] = {gmax_s[col], gmax_s[16 + col]};

    const ushort_t* khp = Khi + ((size_t)b * NM + w * 16 + col) * DK + quad * 8;
    const ushort_t* klp = Klo + ((size_t)b * NM + w * 16 + col) * DK + quad * 8;
    const ushort_t* vp  = Vb + ((size_t)b * DV + dvh * 256 + w * 64 + col) * NM + quad * 8;

    const f32x4 zero4 = {0.f, 0.f, 0.f, 0.f};
    f32x4 accO[4][2];
#pragma unroll
    for (int vt = 0; vt < 4; ++vt)
#pragma unroll
        for (int qt = 0; qt < 2; ++qt) accO[vt][qt] = zero4;

    // K fragments for iter 0
    short8 kh_cur[4], kl_cur[4];
#pragma unroll
    for (int ks = 0; ks < 4; ++ks) {
        kh_cur[ks] = *(const short8*)(khp + ks * 32);
        kl_cur[ks] = *(const short8*)(klp + ks * 32);
    }

    for (int it = 0; it < nit; ++it) {
        const int mb = it * 64;
        const int par = it & 1;

        // V for THIS iter — issued early, consumed after the barrier
        short8 vf[4][2];
#pragma unroll
        for (int vt = 0; vt < 4; ++vt)
#pragma unroll
            for (int ks = 0; ks < 2; ++ks)
                vf[vt][ks] = *(const short8*)(vp + (size_t)(vt * 16) * NM + mb + ks * 32);

        // K for NEXT iter
        const int mb_n = (it + 1 < nit) ? (it + 1) * 64 : 0;
        short8 kh_nxt[4], kl_nxt[4];
#pragma unroll
        for (int ks = 0; ks < 4; ++ks) {
            kh_nxt[ks] = *(const short8*)(khp + (size_t)mb_n * DK + ks * 32);
            kl_nxt[ks] = *(const short8*)(klp + (size_t)mb_n * DK + ks * 32);
        }

        // QK with current K
        f32x4 accS[2];
        accS[0] = zero4; accS[1] = zero4;
#pragma unroll
        for (int ks = 0; ks < 4; ++ks) {
            accS[0] = __builtin_amdgcn_mfma_f32_16x16x32_bf16(kh_cur[ks], qfh[0][ks], accS[0], 0, 0, 0);
            accS[1] = __builtin_amdgcn_mfma_f32_16x16x32_bf16(kh_cur[ks], qfh[1][ks], accS[1], 0, 0, 0);
            accS[0] = __builtin_amdgcn_mfma_f32_16x16x32_bf16(kh_cur[ks], qfl[0][ks], accS[0], 0, 0, 0);
            accS[1] = __builtin_amdgcn_mfma_f32_16x16x32_bf16(kh_cur[ks], qfl[1][ks], accS[1], 0, 0, 0);
            accS[0] = __builtin_amdgcn_mfma_f32_16x16x32_bf16(kl_cur[ks], qfh[0][ks], accS[0], 0, 0, 0);
            accS[1] = __builtin_amdgcn_mfma_f32_16x16x32_bf16(kl_cur[ks], qfh[1][ks], accS[1], 0, 0, 0);
        }

        // P = exp(s - gmax) -> LDS (parity buffer)
        const int mrow = mb + w * 16 + quad * 4;
#pragma unroll
        for (int qt = 0; qt < 2; ++qt) {
            float p[4];
#pragma unroll
            for (int r = 0; r < 4; ++r)
                p[r] = (mrow + r < cnt) ? __expf(accS[qt][r] * 40.0f - gmax[qt]) : 0.0f;
            ushort4 pk;
            pk.x = f2bf(p[0]); pk.y = f2bf(p[1]);
            pk.z = f2bf(p[2]); pk.w = f2bf(p[3]);
            *(ushort4*)&P_s[par][qt * 16 + col][w * 16 + quad * 4] = pk;
        }
        __syncthreads();

        // PV with prefetched V
#pragma unroll
        for (int ks = 0; ks < 2; ++ks) {
            short8 b0 = *(const short8*)&P_s[par][col][ks * 32 + quad * 8];
            short8 b1 = *(const short8*)&P_s[par][16 + col][ks * 32 + quad * 8];
#pragma unroll
            for (int vt = 0; vt < 4; ++vt) {
                accO[vt][0] = __builtin_amdgcn_mfma_f32_16x16x32_bf16(vf[vt][ks], b0, accO[vt][0], 0, 0, 0);
                accO[vt][1] = __builtin_amdgcn_mfma_f32_16x16x32_bf16(vf[vt][ks], b1, accO[vt][1], 0, 0, 0);
            }
        }

#pragma unroll
        for (int ks = 0; ks < 4; ++ks) { kh_cur[ks] = kh_nxt[ks]; kl_cur[ks] = kl_nxt[ks]; }
    }

    // epilogue: normalized, gated fp32 output
#pragma unroll
    for (int qt = 0; qt < 2; ++qt) {
        const int q = qb + qt * 16 + col;
        const float g = grinv_s[qt * 16 + col];
#pragma unroll
        for (int vt = 0; vt < 4; ++vt)
#pragma unroll
            for (int r = 0; r < 4; ++r) {
                int dv = dvh * 256 + w * 64 + vt * 16 + quad * 4 + r;
                out[((size_t)b * DV + dv) * NQ + q] = accO[vt][qt][r] * g;
            }
    }
}

// ---------------------------------------------------------------------------
extern "C" void kernel_launch(void* const* d_in, const int* in_sizes, int n_in,
                              void* d_out, int out_size, void* d_ws, size_t ws_size,
                              hipStream_t stream) {
    const float* qkey  = (const float*)d_in[0];
    // d_in[1] (qval) unused by the reference
    const int*   qmask = (const int*)d_in[2];
    const float* mkey  = (const float*)d_in[3];
    const float* mval  = (const float*)d_in[4];
    const int*   mmask = (const int*)d_in[5];
    float* out = (float*)d_out;

    char* ws = (char*)d_ws;
    size_t off = 0;
    const size_t QS = (size_t)BATCH * NQ * DK * 2;
    const size_t KS = (size_t)BATCH * NM * DK * 2;
    const size_t VS = (size_t)BATCH * DV * NM * 2;
    ushort_t* Qhi = (ushort_t*)(ws + off); off += QS;
    ushort_t* Qlo = (ushort_t*)(ws + off); off += QS;
    ushort_t* Khi = (ushort_t*)(ws + off); off += KS;
    ushort_t* Klo = (ushort_t*)(ws + off); off += KS;
    ushort_t* Vc  = (ushort_t*)(ws + off); off += VS;
    float* mpart  = (float*)(ws + off); off += (size_t)BATCH * NCHUNK * NQ * 4;
    float* lpart  = (float*)(ws + off); off += (size_t)BATCH * NCHUNK * NQ * 4;
    int* cidx     = (int*)(ws + off); off += (size_t)BATCH * NM * 4;
    int* cpos     = (int*)(ws + off); off += (size_t)BATCH * NM * 4;
    int* cnts     = (int*)(ws + off); off += 64;
    int* qflags   = (int*)(ws + off); off += 64;

    scan_kernel<<<BATCH, 1024, 0, stream>>>(qmask, mmask, cidx, cpos, cnts, qflags);

    dim3 gq(NQ / 32, DK / 32, BATCH);
    prep_q_kernel<<<gq, 256, 0, stream>>>(qkey, Qhi, Qlo);
    dim3 gk(NM / 32, DK / 32, BATCH);
    prep_k_kernel<<<gk, 256, 0, stream>>>(mkey, mmask, cpos, Khi, Klo);

    const int vblocks = (int)(((size_t)BATCH * DV * (NM / 4)) / 256);
    prep_v_kernel<<<vblocks, 256, 0, stream>>>(mval, cidx, cnts, Vc);

    dim3 gs(NQ / 32, NCHUNK, BATCH);
    stats_kernel<<<gs, 256, 0, stream>>>(Qhi, Qlo, Khi, Klo, cnts, mpart, lpart);

    // 512 blocks (2 per CU); (b, dvh) combos XCD-swizzled via bid&3
    pv_kernel<<<(NQ / 32) * 4, 256, 0, stream>>>(
        Qhi, Qlo, Khi, Klo, Vc, cnts, qflags, qmask, mpart, lpart, out);
}

// Round 8
// 359.825 us; speedup vs baseline: 1.3453x; 1.1991x over previous
//
#include <hip/hip_runtime.h>

#define NQ 4096
#define NM 8192
#define DK 128
#define DV 512
#define BATCH 2
#define KROW 272            // padded K row bytes (256 data + 16 pad)
#define KTILE (64 * KROW)   // 17408 B = 17 x 1KB chunks
#define KCH 17
#define VTILE 16384         // shorts per (b, mtile, dvh) V tile: 256*64

typedef __attribute__((ext_vector_type(8))) short short8;
typedef __attribute__((ext_vector_type(4))) float f32x4;
typedef unsigned short ushort_t;

static __device__ __forceinline__ unsigned short f2bf(float x) {
    union { float f; unsigned int u; } c; c.f = x;
    unsigned int u = c.u;
    return (unsigned short)((u + 0x7FFFu + ((u >> 16) & 1u)) >> 16);
}
static __device__ __forceinline__ float bf2f(unsigned short h) {
    union { unsigned int u; float f; } c; c.u = ((unsigned int)h) << 16;
    return c.f;
}
// async global->LDS DMA, 16B per lane; lds dst must be wave-uniform base
static __device__ __forceinline__ void glds16(const void* g, void* l) {
    __builtin_amdgcn_global_load_lds(
        (const __attribute__((address_space(1))) unsigned int*)g,
        (__attribute__((address_space(3))) unsigned int*)l, 16, 0, 0);
}

// ---------------------------------------------------------------------------
// scan: per-batch compaction of mmask (shfl wave scans).
// ---------------------------------------------------------------------------
__global__ __launch_bounds__(1024) void scan_kernel(
    const int* __restrict__ qmask, const int* __restrict__ mmask,
    int* __restrict__ cidx, int* __restrict__ cpos,
    int* __restrict__ cnts, int* __restrict__ qflags) {
    const int b = blockIdx.x;
    const int t = threadIdx.x;
    const int lane = t & 63;
    const int w = t >> 6;
    __shared__ int wsum[16];
    __shared__ int qsh;

    const int* mp = mmask + b * NM;
    const int base = t * 8;
    int val[8];
#pragma unroll
    for (int i = 0; i < 8; ++i) val[i] = (mp[base + i] != 0);
    int c0 = 0;
#pragma unroll
    for (int i = 0; i < 8; ++i) c0 += val[i];

    int c = c0;
#pragma unroll
    for (int off = 1; off < 64; off <<= 1) {
        int n = __shfl_up(c, off, 64);
        if (lane >= off) c += n;
    }
    if (lane == 63) wsum[w] = c;
    if (t == 0) qsh = 0;
    __syncthreads();
    if (t == 0) {
        int s = 0;
#pragma unroll
        for (int i = 0; i < 16; ++i) { s += wsum[i]; wsum[i] = s; }
    }
    __syncthreads();
    const int wbase = (w == 0) ? 0 : wsum[w - 1];
    int run = wbase + (c - c0);
#pragma unroll
    for (int i = 0; i < 8; ++i) {
        int m = base + i;
        cpos[b * NM + m] = run;
        if (val[i]) { cidx[b * NM + run] = m; ++run; }
    }

    int qa = 0;
    for (int i = t; i < NQ; i += 1024) qa |= (qmask[b * NQ + i] != 0);
    if (qa) atomicOr(&qsh, 1);
    __syncthreads();
    if (t == 0) { cnts[b] = wsum[15]; qflags[b] = qsh; }
}

// ---------------------------------------------------------------------------
// prep Q: transpose [B][DK][NQ] fp32 -> [B][q][DK] bf16 hi/lo (dense rows)
// ---------------------------------------------------------------------------
__global__ __launch_bounds__(256) void prep_q_kernel(
    const float* __restrict__ src, ushort_t* __restrict__ hi,
    ushort_t* __restrict__ lo) {
    const int b = blockIdx.z;
    const int d0 = blockIdx.y * 32;
    const int n0 = blockIdx.x * 32;
    __shared__ float t32[32][33];
    for (int l = threadIdx.x; l < 1024; l += 256) {
        int r = l >> 5, c = l & 31;
        t32[r][c] = src[((size_t)b * DK + d0 + r) * NQ + n0 + c];
    }
    __syncthreads();
    for (int l = threadIdx.x; l < 1024; l += 256) {
        int r = l >> 5, c = l & 31;
        float f = t32[c][r];
        unsigned short h = f2bf(f);
        unsigned short lw = f2bf(f - bf2f(h));
        size_t off = ((size_t)b * NQ + n0 + r) * DK + d0 + c;
        hi[off] = h;
        lo[off] = lw;
    }
}

// ---------------------------------------------------------------------------
// prep K: transpose + compacting gather -> PADDED image [B][m'][136 shorts]
// (272 B rows: 17 x 1KB chunks per 64-row tile, DMA + bank friendly)
// ---------------------------------------------------------------------------
__global__ __launch_bounds__(256) void prep_k_kernel(
    const float* __restrict__ src, const int* __restrict__ mmask,
    const int* __restrict__ cpos,
    ushort_t* __restrict__ hi, ushort_t* __restrict__ lo) {
    const int b = blockIdx.z;
    const int d0 = blockIdx.y * 32;
    const int n0 = blockIdx.x * 32;
    __shared__ float t32[32][33];
    for (int l = threadIdx.x; l < 1024; l += 256) {
        int r = l >> 5, c = l & 31;
        t32[r][c] = src[((size_t)b * DK + d0 + r) * NM + n0 + c];
    }
    __syncthreads();
    for (int l = threadIdx.x; l < 1024; l += 256) {
        int r = l >> 5, c = l & 31;
        int m = n0 + r;
        if (mmask[b * NM + m] != 0) {
            int pos = cpos[b * NM + m];
            float f = t32[c][r];
            unsigned short h = f2bf(f);
            unsigned short lw = f2bf(f - bf2f(h));
            size_t off = ((size_t)(b * NM + pos)) * 136 + d0 + c;
            hi[off] = h;
            lo[off] = lw;
        }
    }
}

// ---------------------------------------------------------------------------
// prep V: gather + convert -> tile-major [b][mtile][dvh][256 dv][64 m] bf16
// grid (NM/64, DV/64, B), 256 thr: thread = (dv row, 16-m quarter)
// ---------------------------------------------------------------------------
__global__ __launch_bounds__(256) void prep_v_kernel(
    const float* __restrict__ src, const int* __restrict__ cidx,
    const int* __restrict__ cnts, ushort_t* __restrict__ dst) {
    const int mt = blockIdx.x;
    const int dvb = blockIdx.y;
    const int b = blockIdx.z;
    const int cnt = cnts[b];
    const int tr = threadIdx.x >> 2;
    const int part = threadIdx.x & 3;
    const int dv = dvb * 64 + tr;
    const int dvh = dv >> 8, rr = dv & 255;

    const float* row = src + ((size_t)b * DV + dv) * NM;
    const int* cx = cidx + b * NM + mt * 64 + part * 16;
    ushort_t o[16];
#pragma unroll
    for (int i = 0; i < 16; ++i) {
        int m = mt * 64 + part * 16 + i;
        int idx = (m < cnt) ? cx[i] : 0;
        o[i] = (m < cnt) ? f2bf(row[idx]) : (ushort_t)0;
    }
    ushort_t* dp = dst + ((((size_t)b * (NM / 64) + mt) * 2 + dvh) * 256 + rr) * 64 + part * 16;
    *(short8*)dp = *(short8*)&o[0];
    *(short8*)(dp + 8) = *(short8*)&o[8];
}

// ---------------------------------------------------------------------------
// stats: per-(q-tile, half) softmax stats with LDS-staged K (global_load_lds).
// Zero shfls/softmax in loop: lane-local online (m,l); merge at end.
// grid 512 = 128 qt x (2 halves x 2 b), 256 thr.
// ---------------------------------------------------------------------------
__global__ __launch_bounds__(256, 4) void stats_kernel(
    const ushort_t* __restrict__ Qhi, const ushort_t* __restrict__ Qlo,
    const char* __restrict__ KhiI, const char* __restrict__ KloI,
    const int* __restrict__ cnts,
    float* __restrict__ mpart, float* __restrict__ lpart) {
    const int t = threadIdx.x;
    const int lane = t & 63;
    const int w = t >> 6;
    const int quad = lane >> 4;
    const int col = lane & 15;
    const int bid = blockIdx.x;
    const int cmb = bid & 3;
    const int half = cmb & 1;
    const int b = cmb >> 1;
    const int qb = (bid >> 2) * 32;

    const int cnt = cnts[b];
    const int nit = (cnt + 63) >> 6;
    const int it0 = half ? (nit + 1) >> 1 : 0;
    const int it1 = half ? nit : (nit + 1) >> 1;

    __shared__ __align__(16) char KhS[KTILE];
    __shared__ __align__(16) char KlS[KTILE];
    __shared__ float red_m[4][32], red_l[4][32];

    short8 qfh[2][4], qfl[2][4];
    {
        const ushort_t* qhp = Qhi + ((size_t)b * NQ + qb) * DK;
        const ushort_t* qlp = Qlo + ((size_t)b * NQ + qb) * DK;
#pragma unroll
        for (int qt = 0; qt < 2; ++qt)
#pragma unroll
            for (int ks = 0; ks < 4; ++ks) {
                size_t off = (size_t)(qt * 16 + col) * DK + ks * 32 + quad * 8;
                qfh[qt][ks] = *(const short8*)(qhp + off);
                qfl[qt][ks] = *(const short8*)(qlp + off);
            }
    }

    const f32x4 zero4 = {0.f, 0.f, 0.f, 0.f};
    float mloc[2] = {-3.0e38f, -3.0e38f};
    float lloc[2] = {0.0f, 0.0f};
    const int lrow = (w * 16 + col) * KROW;

    for (int it = it0; it < it1; ++it) {
        const char* sH = KhiI + ((size_t)(b * NM) + it * 64) * KROW;
        const char* sL = KloI + ((size_t)(b * NM) + it * 64) * KROW;
        for (int j = w; j < KCH; j += 4) {
            glds16(sH + j * 1024 + lane * 16, &KhS[j * 1024]);
            glds16(sL + j * 1024 + lane * 16, &KlS[j * 1024]);
        }
        __syncthreads();   // K tile in LDS

        f32x4 accS[2];
        accS[0] = zero4; accS[1] = zero4;
#pragma unroll
        for (int ks = 0; ks < 4; ++ks) {
            short8 ah = *(const short8*)&KhS[lrow + ks * 64 + quad * 16];
            short8 al = *(const short8*)&KlS[lrow + ks * 64 + quad * 16];
            accS[0] = __builtin_amdgcn_mfma_f32_16x16x32_bf16(ah, qfh[0][ks], accS[0], 0, 0, 0);
            accS[1] = __builtin_amdgcn_mfma_f32_16x16x32_bf16(ah, qfh[1][ks], accS[1], 0, 0, 0);
            accS[0] = __builtin_amdgcn_mfma_f32_16x16x32_bf16(ah, qfl[0][ks], accS[0], 0, 0, 0);
            accS[1] = __builtin_amdgcn_mfma_f32_16x16x32_bf16(ah, qfl[1][ks], accS[1], 0, 0, 0);
            accS[0] = __builtin_amdgcn_mfma_f32_16x16x32_bf16(al, qfh[0][ks], accS[0], 0, 0, 0);
            accS[1] = __builtin_amdgcn_mfma_f32_16x16x32_bf16(al, qfh[1][ks], accS[1], 0, 0, 0);
        }
        const int mrow = it * 64 + w * 16 + quad * 4;
#pragma unroll
        for (int qt = 0; qt < 2; ++qt) {
            float s[4];
            float tm = -3.0e38f;
#pragma unroll
            for (int r = 0; r < 4; ++r) {
                s[r] = (mrow + r < cnt) ? accS[qt][r] * 40.0f : -3.0e38f;
                tm = fmaxf(tm, s[r]);
            }
            float mn = fmaxf(mloc[qt], tm);
            float ps = 0.f;
#pragma unroll
            for (int r = 0; r < 4; ++r)
                ps += (mrow + r < cnt) ? __expf(s[r] - mn) : 0.0f;
            lloc[qt] = lloc[qt] * __expf(mloc[qt] - mn) + ps;
            mloc[qt] = mn;
        }
        __syncthreads();   // K tile consumed by all waves
    }

#pragma unroll
    for (int qt = 0; qt < 2; ++qt) {
        float m = mloc[qt], l = lloc[qt];
#pragma unroll
        for (int d = 16; d <= 32; d <<= 1) {
            float mo = __shfl_xor(m, d, 64);
            float lo = __shfl_xor(l, d, 64);
            float M = fmaxf(m, mo);
            l = l * __expf(m - M) + lo * __expf(mo - M);
            m = M;
        }
        if (lane < 16) { red_m[w][qt * 16 + col] = m; red_l[w][qt * 16 + col] = l; }
    }
    __syncthreads();
    if (t < 32) {
        float M = -3.0e38f;
#pragma unroll
        for (int ww = 0; ww < 4; ++ww) M = fmaxf(M, red_m[ww][t]);
        float L = 0.f;
#pragma unroll
        for (int ww = 0; ww < 4; ++ww)
            L += red_l[ww][t] * __expf(red_m[ww][t] - M);
        size_t so = ((size_t)(b * 2 + half)) * NQ + qb + t;
        mpart[so] = M;
        lpart[so] = L;
    }
}

// ---------------------------------------------------------------------------
// pv: m97-style K-staging (global_load_lds, single buffer, 2 barriers/iter),
// V tile-major register loads, P single-buffer LDS. q-tile 32, dv-half 256,
// m-tile 64, 256 thr, grid 512, XCD swizzle. Writes final fp32 output.
// ---------------------------------------------------------------------------
__global__ __launch_bounds__(256, 3) void pv_kernel(
    const ushort_t* __restrict__ Qhi, const ushort_t* __restrict__ Qlo,
    const char* __restrict__ KhiI, const char* __restrict__ KloI,
    const ushort_t* __restrict__ Vimg, const int* __restrict__ cnts,
    const int* __restrict__ qflags, const int* __restrict__ qmask,
    const float* __restrict__ mpart, const float* __restrict__ lpart,
    float* __restrict__ out) {
    const int t = threadIdx.x;
    const int lane = t & 63;
    const int w = t >> 6;
    const int quad = lane >> 4;
    const int col = lane & 15;
    const int bid = blockIdx.x;
    const int cmb = bid & 3;
    const int b = cmb >> 1;
    const int dvh = cmb & 1;
    const int qb = (bid >> 2) * 32;

    const int cnt = cnts[b];
    const int nit = (cnt + 63) >> 6;

    __shared__ __align__(16) char KhS[KTILE];
    __shared__ __align__(16) char KlS[KTILE];
    __shared__ __align__(16) ushort_t P_s[32][68];
    __shared__ float gmax_s[32], grinv_s[32];

    if (t < 32) {
        const int q = qb + t;
        float M = -3.0e38f, L = 0.f;
#pragma unroll
        for (int c = 0; c < 2; ++c) {
            size_t so = ((size_t)(b * 2 + c)) * NQ + q;
            float mc = mpart[so], lc = lpart[so];
            float Mn = fmaxf(M, mc);
            L = L * __expf(M - Mn) + lc * __expf(mc - Mn);
            M = Mn;
        }
        bool valid = (qflags[b] != 0) && (cnt > 0) && (qmask[b * NQ + q] != 0) && (L > 0.f);
        gmax_s[t] = M;
        grinv_s[t] = valid ? 1.0f / L : 0.0f;
    }

    short8 qfh[2][4], qfl[2][4];
    {
        const ushort_t* qhp = Qhi + ((size_t)b * NQ + qb) * DK;
        const ushort_t* qlp = Qlo + ((size_t)b * NQ + qb) * DK;
#pragma unroll
        for (int qt = 0; qt < 2; ++qt)
#pragma unroll
            for (int ks = 0; ks < 4; ++ks) {
                size_t off = (size_t)(qt * 16 + col) * DK + ks * 32 + quad * 8;
                qfh[qt][ks] = *(const short8*)(qhp + off);
                qfl[qt][ks] = *(const short8*)(qlp + off);
            }
    }
    __syncthreads();
    const float gmax[2] = {gmax_s[col], gmax_s[16 + col]};

    // per-lane V base within a tile: row = w*64 + col, offset quad*8 shorts
    const ushort_t* vlane = Vimg + (size_t)(w * 64 + col) * 64 + quad * 8;
    const size_t vtstride = (size_t)2 * VTILE;   // per-mtile stride (both dvh)
    const size_t vbase0 = ((size_t)b * (NM / 64) * 2 + dvh) * VTILE;

    const f32x4 zero4 = {0.f, 0.f, 0.f, 0.f};
    f32x4 accO[4][2];
#pragma unroll
    for (int vt = 0; vt < 4; ++vt)
#pragma unroll
        for (int qt = 0; qt < 2; ++qt) accO[vt][qt] = zero4;

    const int lrow = (w * 16 + col) * KROW;

    for (int it = 0; it < nit; ++it) {
        // ---- issue K DMA for this iter ----
        const char* sH = KhiI + ((size_t)(b * NM) + it * 64) * KROW;
        const char* sL = KloI + ((size_t)(b * NM) + it * 64) * KROW;
        for (int j = w; j < KCH; j += 4) {
            glds16(sH + j * 1024 + lane * 16, &KhS[j * 1024]);
            glds16(sL + j * 1024 + lane * 16, &KlS[j * 1024]);
        }
        // ---- V regs (first half) ----
        const ushort_t* vp = Vimg + vbase0 + (size_t)it * vtstride +
                             (size_t)(w * 64 + col) * 64 + quad * 8;
        short8 vf[4][2];
#pragma unroll
        for (int vt = 0; vt < 2; ++vt)
#pragma unroll
            for (int ks = 0; ks < 2; ++ks)
                vf[vt][ks] = *(const short8*)(vp + vt * (16 * 64) + ks * 32);
        __syncthreads();   // barrier1: K tile in LDS (DMA drained)

        // ---- V regs (second half), covered by QK compute ----
#pragma unroll
        for (int vt = 2; vt < 4; ++vt)
#pragma unroll
            for (int ks = 0; ks < 2; ++ks)
                vf[vt][ks] = *(const short8*)(vp + vt * (16 * 64) + ks * 32);

        // ---- QK from LDS ----
        f32x4 accS[2];
        accS[0] = zero4; accS[1] = zero4;
#pragma unroll
        for (int ks = 0; ks < 4; ++ks) {
            short8 ah = *(const short8*)&KhS[lrow + ks * 64 + quad * 16];
            short8 al = *(const short8*)&KlS[lrow + ks * 64 + quad * 16];
            accS[0] = __builtin_amdgcn_mfma_f32_16x16x32_bf16(ah, qfh[0][ks], accS[0], 0, 0, 0);
            accS[1] = __builtin_amdgcn_mfma_f32_16x16x32_bf16(ah, qfh[1][ks], accS[1], 0, 0, 0);
            accS[0] = __builtin_amdgcn_mfma_f32_16x16x32_bf16(ah, qfl[0][ks], accS[0], 0, 0, 0);
            accS[1] = __builtin_amdgcn_mfma_f32_16x16x32_bf16(ah, qfl[1][ks], accS[1], 0, 0, 0);
            accS[0] = __builtin_amdgcn_mfma_f32_16x16x32_bf16(al, qfh[0][ks], accS[0], 0, 0, 0);
            accS[1] = __builtin_amdgcn_mfma_f32_16x16x32_bf16(al, qfh[1][ks], accS[1], 0, 0, 0);
        }

        // ---- P = exp(s - gmax) -> LDS ----
        const int mrow = it * 64 + w * 16 + quad * 4;
#pragma unroll
        for (int qt = 0; qt < 2; ++qt) {
            float p[4];
#pragma unroll
            for (int r = 0; r < 4; ++r)
                p[r] = (mrow + r < cnt) ? __expf(accS[qt][r] * 40.0f - gmax[qt]) : 0.0f;
            ushort4 pk;
            pk.x = f2bf(p[0]); pk.y = f2bf(p[1]);
            pk.z = f2bf(p[2]); pk.w = f2bf(p[3]);
            *(ushort4*)&P_s[qt * 16 + col][w * 16 + quad * 4] = pk;
        }
        __syncthreads();   // barrier2: P ready; K tile free (QK done by all)

        // ---- PV ----
#pragma unroll
        for (int ks = 0; ks < 2; ++ks) {
            short8 b0 = *(const short8*)&P_s[col][ks * 32 + quad * 8];
            short8 b1 = *(const short8*)&P_s[16 + col][ks * 32 + quad * 8];
#pragma unroll
            for (int vt = 0; vt < 4; ++vt) {
                accO[vt][0] = __builtin_amdgcn_mfma_f32_16x16x32_bf16(vf[vt][ks], b0, accO[vt][0], 0, 0, 0);
                accO[vt][1] = __builtin_amdgcn_mfma_f32_16x16x32_bf16(vf[vt][ks], b1, accO[vt][1], 0, 0, 0);
            }
        }
    }

    // ---- epilogue: normalized, gated fp32 output ----
#pragma unroll
    for (int qt = 0; qt < 2; ++qt) {
        const int q = qb + qt * 16 + col;
        const float g = grinv_s[qt * 16 + col];
#pragma unroll
        for (int vt = 0; vt < 4; ++vt)
#pragma unroll
            for (int r = 0; r < 4; ++r) {
                int dv = dvh * 256 + w * 64 + vt * 16 + quad * 4 + r;
                out[((size_t)b * DV + dv) * NQ + q] = accO[vt][qt][r] * g;
            }
    }
}

// ---------------------------------------------------------------------------
extern "C" void kernel_launch(void* const* d_in, const int* in_sizes, int n_in,
                              void* d_out, int out_size, void* d_ws, size_t ws_size,
                              hipStream_t stream) {
    const float* qkey  = (const float*)d_in[0];
    // d_in[1] (qval) unused by the reference
    const int*   qmask = (const int*)d_in[2];
    const float* mkey  = (const float*)d_in[3];
    const float* mval  = (const float*)d_in[4];
    const int*   mmask = (const int*)d_in[5];
    float* out = (float*)d_out;

    char* ws = (char*)d_ws;
    size_t off = 0;
    const size_t QS = (size_t)BATCH * NQ * DK * 2;          // 2 MB
    const size_t KS = (size_t)BATCH * NM * KROW;            // 4.46 MB (padded image)
    const size_t VS = (size_t)BATCH * (NM / 64) * 2 * VTILE * 2;  // 16.8 MB
    ushort_t* Qhi = (ushort_t*)(ws + off); off += QS;
    ushort_t* Qlo = (ushort_t*)(ws + off); off += QS;
    char* KhiI    = (char*)(ws + off); off += KS;
    char* KloI    = (char*)(ws + off); off += KS;
    ushort_t* Vc  = (ushort_t*)(ws + off); off += VS;
    float* mpart  = (float*)(ws + off); off += (size_t)BATCH * 2 * NQ * 4;
    float* lpart  = (float*)(ws + off); off += (size_t)BATCH * 2 * NQ * 4;
    int* cidx     = (int*)(ws + off); off += (size_t)BATCH * NM * 4;
    int* cpos     = (int*)(ws + off); off += (size_t)BATCH * NM * 4;
    int* cnts     = (int*)(ws + off); off += 64;
    int* qflags   = (int*)(ws + off); off += 64;

    scan_kernel<<<BATCH, 1024, 0, stream>>>(qmask, mmask, cidx, cpos, cnts, qflags);

    dim3 gq(NQ / 32, DK / 32, BATCH);
    prep_q_kernel<<<gq, 256, 0, stream>>>(qkey, Qhi, Qlo);
    dim3 gk(NM / 32, DK / 32, BATCH);
    prep_k_kernel<<<gk, 256, 0, stream>>>(mkey, mmask, cpos,
                                          (ushort_t*)KhiI, (ushort_t*)KloI);

    dim3 gv(NM / 64, DV / 64, BATCH);
    prep_v_kernel<<<gv, 256, 0, stream>>>(mval, cidx, cnts, Vc);

    stats_kernel<<<(NQ / 32) * 4, 256, 0, stream>>>(
        Qhi, Qlo, KhiI, KloI, cnts, mpart, lpart);

    pv_kernel<<<(NQ / 32) * 4, 256, 0, stream>>>(
        Qhi, Qlo, KhiI, KloI, Vc, cnts, qflags, qmask, mpart, lpart, out);
}